// Round 15
// baseline (43.679 us; speedup 1.0000x reference)
//
#include <hip/hip_runtime.h>
#include <hip/hip_fp16.h>
#include <math.h>

#define EMB_DIM 500
#define TWO_D 1000
#define D4 125                 // float4 groups per half-row (500/4)
#define ROW_F4 250             // float4 per entity row (1000/4)
#define NUM_ENTITIES 14541
#define B_SIZE 16
#define GAMMA_F 12.0f
// PI / ((GAMMA + 2) / EMB_DIM) = pi / 0.028
#define PHASE_SCALE 112.19973762820692f
#define ROT_HALFS (B_SIZE * D4 * 8)   // 16000 halfs = 32000 B
#define NP (B_SIZE * NUM_ENTITIES)    // 232656 partials per d-half

// ---------------------------------------------------------------------------
// Kernel 1: precompute rotated head embeddings as fp16, interleaved layout
// rot[b][d4][0..3] = re(4*d4 .. 4*d4+3), rot[b][d4][4..7] = im(...)
// ---------------------------------------------------------------------------
__global__ __launch_bounds__(256) void rot_precompute(
    const int* __restrict__ all_h, const int* __restrict__ all_r,
    const float* __restrict__ eemb, const float* __restrict__ remb,
    __half* __restrict__ rot)
{
    int i = blockIdx.x * 256 + threadIdx.x;
    if (i >= B_SIZE * EMB_DIM) return;
    int b = i / EMB_DIM;
    int d = i - b * EMB_DIM;
    int h = all_h[b];
    int r = all_r[b];
    float re_h = eemb[h * TWO_D + d];
    float im_h = eemb[h * TWO_D + EMB_DIM + d];
    float ph = remb[r * EMB_DIM + d] * PHASE_SCALE;
    float s, c;
    sincosf(ph, &s, &c);
    int base = ((b * D4 + (d >> 2)) << 3) + (d & 3);
    rot[base]     = __float2half(re_h * c - im_h * s);  // re_rot
    rot[base + 4] = __float2half(re_h * s + im_h * c);  // im_rot
}

// ---------------------------------------------------------------------------
// Kernel 2: D-SPLIT of the R9 winner. Block = (etile of 16 ents, d-half).
// Wave keeps 4 ents x 16 b (16 evals per ds_read — the measured optimum)
// but covers only one 64-wide d4 half -> per-wave work halves while BLOCK
// SUPPLY DOUBLES (1818 blocks = 7.1/CU vs 3.55; LDS 16 KB -> 10/CU cap).
// Theory: R13(sched)/R14(inst-count) neutral => plateau is resident-wave
// starvation + dependent chains; this is the clean occupancy-only test
// (R12 confounded supply with 8-evals/read amortization loss).
// Writes per-d-half partials to ws; combine() folds them into out.
// ---------------------------------------------------------------------------
__global__ __launch_bounds__(256) void rotate_partial(
    const float* __restrict__ eemb,
    const __half* __restrict__ rot,
    float* __restrict__ partial)         // [2][B_SIZE][NUM_ENTITIES]
{
    __shared__ float4 lrot4[B_SIZE * 64];  // 16384 B: [b][j], j = d4 - dh*64

    const int tid = threadIdx.x;
    const int dh    = blockIdx.x & 1;
    const int etile = blockIdx.x >> 1;

    // Stage this d-half's stripe of the rot table: [16][64] float4.
    {
        const float4* src = (const float4*)rot;
        for (int i = tid; i < B_SIZE * 64; i += 256) {
            int b = i >> 6;
            int j = i & 63;
            int d4s = dh * 64 + j;
            if (d4s > D4 - 1) d4s = D4 - 1;      // clamp (dh=1 has 61 valid)
            lrot4[i] = src[b * D4 + d4s];
        }
    }
    __syncthreads();

    const int lane = tid & 63;
    const int wave = tid >> 6;
    const int e0 = etile * 16 + wave * 4;

    int e[4];
#pragma unroll
    for (int k = 0; k < 4; ++k) {
        int ek = e0 + k;
        e[k] = (ek < NUM_ENTITIES) ? ek : (NUM_ENTITIES - 1);
    }

    const int d4_raw = dh * 64 + lane;
    const bool valid = (d4_raw < D4);
    const int d4c = valid ? d4_raw : (D4 - 1);
    const float mask = valid ? 1.0f : 0.0f;

    const float4* ee4 = (const float4*)eemb;

    float4 tre[4], tim[4];
#pragma unroll
    for (int k = 0; k < 4; ++k) {
        const int rb = e[k] * ROW_F4;
        tre[k] = ee4[rb + d4c];
        tim[k] = ee4[rb + D4 + d4c];
    }

    float v[64];                         // acc[k][b]: idx = k*16+b
#pragma unroll
    for (int i = 0; i < 64; ++i) v[i] = 0.0f;

#pragma unroll
    for (int b = 0; b < 16; ++b) {
        float4 rv = lrot4[b * 64 + lane];   // clamped stage = finite values
        __half2 p0 = __builtin_bit_cast(__half2, rv.x);
        __half2 p1 = __builtin_bit_cast(__half2, rv.y);
        __half2 p2 = __builtin_bit_cast(__half2, rv.z);
        __half2 p3 = __builtin_bit_cast(__half2, rv.w);
        float rre0 = __low2float(p0), rre1 = __high2float(p0);
        float rre2 = __low2float(p1), rre3 = __high2float(p1);
        float rim0 = __low2float(p2), rim1 = __high2float(p2);
        float rim2 = __low2float(p3), rim3 = __high2float(p3);
#pragma unroll
        for (int k = 0; k < 4; ++k) {
            float dre, dim;
            dre = rre0 - tre[k].x; dim = rim0 - tim[k].x;
            v[k * 16 + b] = fmaf(mask,
                __builtin_amdgcn_sqrtf(dre * dre + dim * dim), v[k * 16 + b]);
            dre = rre1 - tre[k].y; dim = rim1 - tim[k].y;
            v[k * 16 + b] = fmaf(mask,
                __builtin_amdgcn_sqrtf(dre * dre + dim * dim), v[k * 16 + b]);
            dre = rre2 - tre[k].z; dim = rim2 - tim[k].z;
            v[k * 16 + b] = fmaf(mask,
                __builtin_amdgcn_sqrtf(dre * dre + dim * dim), v[k * 16 + b]);
            dre = rre3 - tre[k].w; dim = rim3 - tim[k].w;
            v[k * 16 + b] = fmaf(mask,
                __builtin_amdgcn_sqrtf(dre * dre + dim * dim), v[k * 16 + b]);
        }
    }

    // Halving butterfly: lane L ends holding the full 64-lane sum of v[L].
#pragma unroll
    for (int m = 32; m >= 1; m >>= 1) {
        const bool hi = (lane & m) != 0;
#pragma unroll
        for (int i = 0; i < m; ++i) {
            float give = hi ? v[i] : v[m + i];
            float keep = hi ? v[m + i] : v[i];
            v[i] = keep + __shfl_xor(give, m, 64);
        }
    }

    const int kk = lane >> 4;            // 0..3
    const int bb = lane & 15;            // 0..15
    const int ee = e0 + kk;
    if (ee < NUM_ENTITIES)
        partial[dh * NP + bb * NUM_ENTITIES + ee] = v[0];
}

// ---------------------------------------------------------------------------
// Kernel 3: out = GAMMA - (p0 + p1), float4-vectorized.
// ---------------------------------------------------------------------------
__global__ __launch_bounds__(256) void combine(
    const float* __restrict__ partial, float* __restrict__ out)
{
    int i = blockIdx.x * 256 + threadIdx.x;
    const int n4 = NP / 4;               // 58164
    if (i >= n4) return;
    const float4* p0 = (const float4*)partial;
    const float4* p1 = (const float4*)(partial + NP);
    float4 a = p0[i], b = p1[i];
    float4 r;
    r.x = GAMMA_F - (a.x + b.x);
    r.y = GAMMA_F - (a.y + b.y);
    r.z = GAMMA_F - (a.z + b.z);
    r.w = GAMMA_F - (a.w + b.w);
    ((float4*)out)[i] = r;
}

// ---------------------------------------------------------------------------
// Fallback (ws-starved): R9's proven kernel, rot computed in-kernel.
// ---------------------------------------------------------------------------
__global__ __launch_bounds__(256) void rotate_score_fb(
    const float* __restrict__ eemb,
    const int* __restrict__ all_h, const int* __restrict__ all_r,
    const float* __restrict__ remb,
    float* __restrict__ out)
{
    __shared__ __half lrot[ROT_HALFS];
    const int tid = threadIdx.x;
    for (int i = tid; i < B_SIZE * EMB_DIM; i += 256) {
        int b = i / EMB_DIM;
        int d = i - b * EMB_DIM;
        int h = all_h[b];
        int r = all_r[b];
        float re_h = eemb[h * TWO_D + d];
        float im_h = eemb[h * TWO_D + EMB_DIM + d];
        float ph = remb[r * EMB_DIM + d] * PHASE_SCALE;
        float s, c;
        sincosf(ph, &s, &c);
        int base = ((b * D4 + (d >> 2)) << 3) + (d & 3);
        lrot[base]     = __float2half(re_h * c - im_h * s);
        lrot[base + 4] = __float2half(re_h * s + im_h * c);
    }
    __syncthreads();

    const int lane = tid & 63;
    const int wave = tid >> 6;
    const int e0 = blockIdx.x * 16 + wave * 4;
    int e[4];
#pragma unroll
    for (int k = 0; k < 4; ++k) {
        int ek = e0 + k;
        e[k] = (ek < NUM_ENTITIES) ? ek : (NUM_ENTITIES - 1);
    }
    float v[64];
#pragma unroll
    for (int i = 0; i < 64; ++i) v[i] = 0.0f;
    const float4* lrot4 = (const float4*)lrot;
    const float4* ee4 = (const float4*)eemb;
#pragma unroll
    for (int it = 0; it < 2; ++it) {
        const int d4 = it * 64 + lane;
        if (d4 < D4) {
            float4 tre[4], tim[4];
#pragma unroll
            for (int k = 0; k < 4; ++k) {
                int rb = e[k] * ROW_F4;
                tre[k] = ee4[rb + d4];
                tim[k] = ee4[rb + D4 + d4];
            }
#pragma unroll
            for (int b = 0; b < 16; ++b) {
                float4 rvb = lrot4[b * D4 + d4];
                __half2 p0 = __builtin_bit_cast(__half2, rvb.x);
                __half2 p1 = __builtin_bit_cast(__half2, rvb.y);
                __half2 p2 = __builtin_bit_cast(__half2, rvb.z);
                __half2 p3 = __builtin_bit_cast(__half2, rvb.w);
                float rre0 = __low2float(p0), rre1 = __high2float(p0);
                float rre2 = __low2float(p1), rre3 = __high2float(p1);
                float rim0 = __low2float(p2), rim1 = __high2float(p2);
                float rim2 = __low2float(p3), rim3 = __high2float(p3);
#pragma unroll
                for (int k = 0; k < 4; ++k) {
                    float dre, dim;
                    dre = rre0 - tre[k].x; dim = rim0 - tim[k].x;
                    v[k * 16 + b] += __builtin_amdgcn_sqrtf(dre * dre + dim * dim);
                    dre = rre1 - tre[k].y; dim = rim1 - tim[k].y;
                    v[k * 16 + b] += __builtin_amdgcn_sqrtf(dre * dre + dim * dim);
                    dre = rre2 - tre[k].z; dim = rim2 - tim[k].z;
                    v[k * 16 + b] += __builtin_amdgcn_sqrtf(dre * dre + dim * dim);
                    dre = rre3 - tre[k].w; dim = rim3 - tim[k].w;
                    v[k * 16 + b] += __builtin_amdgcn_sqrtf(dre * dre + dim * dim);
                }
            }
        }
    }
#pragma unroll
    for (int m = 32; m >= 1; m >>= 1) {
        const bool hi = (lane & m) != 0;
#pragma unroll
        for (int i = 0; i < m; ++i) {
            float give = hi ? v[i] : v[m + i];
            float keep = hi ? v[m + i] : v[i];
            v[i] = keep + __shfl_xor(give, m, 64);
        }
    }
    const int kk = lane >> 4;
    const int bb = lane & 15;
    const int ee = e0 + kk;
    if (ee < NUM_ENTITIES) out[bb * NUM_ENTITIES + ee] = GAMMA_F - v[0];
}

extern "C" void kernel_launch(void* const* d_in, const int* in_sizes, int n_in,
                              void* d_out, int out_size, void* d_ws, size_t ws_size,
                              hipStream_t stream) {
    const int*   all_h = (const int*)d_in[0];
    const int*   all_r = (const int*)d_in[1];
    const float* eemb  = (const float*)d_in[2];
    const float* remb  = (const float*)d_in[3];
    float* out = (float*)d_out;

    const size_t part_bytes = (size_t)2 * NP * sizeof(float);       // 1.86 MB
    const size_t rot_bytes  = (size_t)ROT_HALFS * sizeof(__half);   // 32 KB
    if (ws_size >= part_bytes + rot_bytes) {
        float*  part = (float*)d_ws;
        __half* rot  = (__half*)((char*)d_ws + part_bytes);
        rot_precompute<<<(B_SIZE * EMB_DIM + 255) / 256, 256, 0, stream>>>(
            all_h, all_r, eemb, remb, rot);
        int etiles = (NUM_ENTITIES + 15) / 16;   // 909
        rotate_partial<<<etiles * 2, 256, 0, stream>>>(eemb, rot, part);
        combine<<<(NP / 4 + 255) / 256, 256, 0, stream>>>(part, out);
    } else {
        int nblocks = (NUM_ENTITIES + 15) / 16;  // 909
        rotate_score_fb<<<nblocks, 256, 0, stream>>>(
            eemb, all_h, all_r, remb, out);
    }
}